// Round 12
// baseline (461.532 us; speedup 1.0000x reference)
//
#include <hip/hip_runtime.h>

#define NN 50000
#define EE 800000
#define NTILES 12500
#define BPG 384                     // edge_mlp blocks per graph (contiguous ranges)
#define NB 98                       // scan blocks per graph (98*512 >= 50000)
#define NPB 196                     // pre_k blocks per job

typedef _Float16 half8 __attribute__((ext_vector_type(8)));
typedef __attribute__((ext_vector_type(4))) float f32x4;
typedef __attribute__((ext_vector_type(4))) unsigned u32x4;

// order-preserving float->u32 encoding for atomicMax scatter-max
__device__ __forceinline__ unsigned enc(float f) {
    unsigned u = __float_as_uint(f);
    return u ^ (unsigned)(((int)u >> 31) | 0x80000000);
}
__device__ __forceinline__ float dec(unsigned u) {
    unsigned v = (u & 0x80000000u) ? (u & 0x7FFFFFFFu) : ~u;
    return __uint_as_float(v);
}

__global__ void decode_acc(unsigned* __restrict__ acc, int n) {
    int i = blockIdx.x * blockDim.x + threadIdx.x;
    if (i < n) {
        unsigned u = acc[i];
        ((float*)acc)[i] = (u == 0u) ? 0.0f : dec(u);   // empty -> 0.0 (ref)
    }
}

// ---------------- counting sort by destination row ----------------
__global__ void hist_k(const int* __restrict__ ei1, const int* __restrict__ ei2,
                       unsigned* __restrict__ cnt) {          // cnt[2][NN]
    int idx = blockIdx.x * blockDim.x + threadIdx.x;
    if (idx < EE)           atomicAdd(&cnt[ei1[idx]], 1u);
    else if (idx < 2 * EE)  atomicAdd(&cnt[NN + ei2[idx - EE]], 1u);
}

__global__ __launch_bounds__(512)
void partial_k(const unsigned* __restrict__ cnt, unsigned* __restrict__ partial) {
    int g = blockIdx.x / NB, b = blockIdx.x % NB;
    int i = b * 512 + threadIdx.x;
    unsigned x = (i < NN) ? cnt[g * NN + i] : 0u;
    #pragma unroll
    for (int o = 32; o; o >>= 1) x += __shfl_down(x, o, 64);
    __shared__ unsigned ws[8];
    int lane = threadIdx.x & 63, w = threadIdx.x >> 6;
    if (lane == 0) ws[w] = x;
    __syncthreads();
    if (threadIdx.x == 0) {
        unsigned s = 0;
        #pragma unroll
        for (int k = 0; k < 8; ++k) s += ws[k];
        partial[g * NB + b] = s;
    }
}

__global__ __launch_bounds__(128)
void boff_k(const unsigned* __restrict__ partial, unsigned* __restrict__ boff) {
    int g = threadIdx.x >> 6, lane = threadIdx.x & 63;
    const unsigned* p = partial + g * NB;
    unsigned* o = boff + g * NB;
    unsigned x0 = p[lane];
    unsigned v0 = x0;
    #pragma unroll
    for (int d = 1; d < 64; d <<= 1) { unsigned t = __shfl_up(v0, d, 64); if (lane >= d) v0 += t; }
    unsigned sum0 = __shfl(v0, 63, 64);
    unsigned x1 = (64 + lane < NB) ? p[64 + lane] : 0u;
    unsigned v1 = x1;
    #pragma unroll
    for (int d = 1; d < 64; d <<= 1) { unsigned t = __shfl_up(v1, d, 64); if (lane >= d) v1 += t; }
    o[lane] = v0 - x0;
    if (64 + lane < NB) o[64 + lane] = sum0 + v1 - x1;
}

__global__ __launch_bounds__(512)
void cur_k(const unsigned* __restrict__ cnt, const unsigned* __restrict__ boff,
           unsigned* __restrict__ cur) {
    int g = blockIdx.x / NB, b = blockIdx.x % NB;
    int i = b * 512 + threadIdx.x;
    unsigned x = (i < NN) ? cnt[g * NN + i] : 0u;
    int lane = threadIdx.x & 63, w = threadIdx.x >> 6;
    unsigned v = x;
    #pragma unroll
    for (int d = 1; d < 64; d <<= 1) { unsigned t = __shfl_up(v, d, 64); if (lane >= d) v += t; }
    __shared__ unsigned ws[8], wso[8];
    if (lane == 63) ws[w] = v;
    __syncthreads();
    if (threadIdx.x < 8) {
        unsigned s = 0;
        for (int k = 0; k < (int)threadIdx.x; ++k) s += ws[k];
        wso[threadIdx.x] = s;
    }
    __syncthreads();
    if (i < NN) cur[g * NN + i] = boff[g * NB + b] + wso[w] + v - x;
}

__global__ void scatter_k(const int* __restrict__ ei1, const int* __restrict__ ei2,
                          unsigned* __restrict__ cur, uint2* __restrict__ se) {
    int idx = blockIdx.x * blockDim.x + threadIdx.x;
    if (idx < EE) {
        int r = ei1[idx], c = ei1[EE + idx];
        unsigned p = atomicAdd(&cur[r], 1u);
        se[p] = make_uint2((unsigned)r, (unsigned)c);
    } else if (idx < 2 * EE) {
        int e = idx - EE;
        int r = ei2[e], c = ei2[EE + e];
        unsigned p = atomicAdd(&cur[NN + r], 1u);
        se[EE + p] = make_uint2((unsigned)r, (unsigned)c);
    }
}

// ---------------- node-level precompute GEMMs (layer-1 algebra) ----------------
// job 0: a1  = x1 @ (W1top - W1bot) + b1      [NN x 128] f16
// job 1: bb1 = x1 @ W1bot ; job 2: bb2 = x2 @ W1bot
__global__ __launch_bounds__(256)
void pre_k(const float* __restrict__ x1, const float* __restrict__ x2,
           const float* __restrict__ W1, const float* __restrict__ b1,
           _Float16* __restrict__ pre)
{
    const int j  = blockIdx.x / NPB;
    const int bb = blockIdx.x % NPB;
    const float* __restrict__ xs = (j == 2) ? x2 : x1;
    _Float16* __restrict__ out = pre + (size_t)j * NN * 128;

    const int lane = threadIdx.x & 63;
    const int w    = threadIdx.x >> 6;
    const int l15  = lane & 15;
    const int lg   = lane >> 4;
    const int rowbase = bb * 256 + w * 64;

    half8 af[4][2];
    #pragma unroll
    for (int m = 0; m < 4; ++m)
        #pragma unroll
        for (int ks = 0; ks < 2; ++ks) {
            int row = rowbase + 16 * m + l15;
            if (row > NN - 1) row = NN - 1;
            const float* p = xs + (size_t)row * 64 + 32 * ks + 8 * lg;
            half8 r;
            #pragma unroll
            for (int i = 0; i < 8; ++i) r[i] = (_Float16)p[i];
            af[m][ks] = r;
        }

    #pragma unroll 2
    for (int n = 0; n < 8; ++n) {
        half8 bf[2];
        #pragma unroll
        for (int ks = 0; ks < 2; ++ks) {
            half8 r;
            #pragma unroll
            for (int i = 0; i < 8; ++i) {
                int k = 32 * ks + 8 * lg + i;
                int o = 16 * n + l15;
                float wv = (j == 0)
                    ? (W1[(size_t)k * 128 + o] - W1[(size_t)(64 + k) * 128 + o])
                    :  W1[(size_t)(64 + k) * 128 + o];
                r[i] = (_Float16)wv;
            }
            bf[ks] = r;
        }
        float binit = (j == 0) ? b1[16 * n + l15] : 0.0f;
        f32x4 acc[4];
        #pragma unroll
        for (int m = 0; m < 4; ++m) {
            acc[m][0] = binit; acc[m][1] = binit;
            acc[m][2] = binit; acc[m][3] = binit;
        }
        #pragma unroll
        for (int ks = 0; ks < 2; ++ks)
            #pragma unroll
            for (int m = 0; m < 4; ++m)
                acc[m] = __builtin_amdgcn_mfma_f32_16x16x32_f16(
                    af[m][ks], bf[ks], acc[m], 0, 0, 0);
        #pragma unroll
        for (int m = 0; m < 4; ++m)
            #pragma unroll
            for (int r = 0; r < 4; ++r) {
                int row = rowbase + 16 * m + 4 * lg + r;
                if (row < NN)
                    out[(size_t)row * 128 + 16 * n + l15] = (_Float16)acc[m][r];
            }
    }
}

// ---------------- main kernel: sorted edges, transposed L2, run-merged atomics
__global__ __launch_bounds__(256, 3)
void edge_mlp(const _Float16* __restrict__ pre,
              const uint2* __restrict__ se,
              const float* __restrict__ W2, const float* __restrict__ b2,
              unsigned* __restrict__ acc)
{
    __shared__ short h_lds[2][64 * 128];   // 2 x 16 KB, (e&15)<<3 XOR-swizzled
    __shared__ int srow[2][64];

    const int tid  = threadIdx.x;
    const int lane = tid & 63;
    const int l15  = lane & 15;
    const int lg   = lane >> 4;
    const int wid  = tid >> 6;
    const int w_h  = wid & 1;
    const int w_e  = wid >> 1;

    const int g     = (blockIdx.x >= BPG) ? 1 : 0;
    const int bslot = g ? (blockIdx.x - BPG) : blockIdx.x;
    const uint2* __restrict__ sed = se + (size_t)g * EE;
    const _Float16* __restrict__ pa = pre;
    const _Float16* __restrict__ pb = pre + (size_t)(1 + g) * NN * 128;
    const int goff = g * 64;

    const int t0 = (bslot * NTILES) / BPG;
    const int t1 = ((bslot + 1) * NTILES) / BPG;

    // W2^T A-frags (same values as old B-frags): af[s][n], lane->W2[32s+8lg+i][chbase+l15]
    half8 w2f[4][2];
    #pragma unroll
    for (int s = 0; s < 4; ++s)
        #pragma unroll
        for (int n = 0; n < 2; ++n) {
            const float* p = W2 + (size_t)(32 * s + 8 * lg) * 64
                               + (w_h * 32 + 16 * n + l15);
            half8 r;
            #pragma unroll
            for (int i = 0; i < 8; ++i) r[i] = (_Float16)p[i * 64];
            w2f[s][n] = r;
        }
    // bias for transposed D: acc2[m][n][r] is channel w_h*32+16n+4lg+r
    float4 b2v4[2];
    #pragma unroll
    for (int n = 0; n < 2; ++n)
        b2v4[n] = *(const float4*)(b2 + w_h * 32 + 16 * n + 4 * lg);

    const int ge = lane;
    const int gq = wid;
    const int swz = (ge & 15) << 3;

    // ---- prologue ----
    int rcur, ccur, rnext, cnext;
    {
        uint2 a = sed[t0 * 64 + ge];
        rcur = (int)a.x; ccur = (int)a.y;
        int tb = min(t0 + 1, t1 - 1);
        uint2 b = sed[tb * 64 + ge];
        rnext = (int)b.x; cnext = (int)b.y;
    }
    uint4 ga0, ga1, ga2, ga3, gb0, gb1, gb2, gb3;
    {
        const uint4* ap = (const uint4*)(pa + (size_t)rcur * 128 + 32 * gq);
        const uint4* bp = (const uint4*)(pb + (size_t)ccur * 128 + 32 * gq);
        ga0 = ap[0]; ga1 = ap[1]; ga2 = ap[2]; ga3 = ap[3];
        gb0 = bp[0]; gb1 = bp[1]; gb2 = bp[2]; gb3 = bp[3];
    }

    const unsigned zu = 0u;
    int i = 0;
    for (int t = t0; t < t1; ++t, ++i) {
        const int ib = i & 1;
        // ---- A: srow + h tile = relu(a + b) from prefetched regs ----
        if (tid < 64) srow[ib][tid] = rcur;
        {
            short* hrow = &h_lds[ib][ge * 128];
            u32x4 h;
            #define COMBINE(A, B, K)                                           \
                {                                                              \
                    unsigned s0, s1, s2, s3;                                   \
                    asm("v_pk_add_f16 %0, %1, %2" : "=v"(s0) : "v"(A.x), "v"(B.x)); \
                    asm("v_pk_add_f16 %0, %1, %2" : "=v"(s1) : "v"(A.y), "v"(B.y)); \
                    asm("v_pk_add_f16 %0, %1, %2" : "=v"(s2) : "v"(A.z), "v"(B.z)); \
                    asm("v_pk_add_f16 %0, %1, %2" : "=v"(s3) : "v"(A.w), "v"(B.w)); \
                    asm("v_pk_max_f16 %0, %1, %2" : "=v"(s0) : "v"(s0), "v"(zu));   \
                    asm("v_pk_max_f16 %0, %1, %2" : "=v"(s1) : "v"(s1), "v"(zu));   \
                    asm("v_pk_max_f16 %0, %1, %2" : "=v"(s2) : "v"(s2), "v"(zu));   \
                    asm("v_pk_max_f16 %0, %1, %2" : "=v"(s3) : "v"(s3), "v"(zu));   \
                    h[0] = s0; h[1] = s1; h[2] = s2; h[3] = s3;                \
                    *(u32x4*)&hrow[(32 * gq + 8 * K) ^ swz] = h;               \
                }
            COMBINE(ga0, gb0, 0)
            COMBINE(ga1, gb1, 1)
            COMBINE(ga2, gb2, 2)
            COMBINE(ga3, gb3, 3)
            #undef COMBINE
        }

        // ---- B: rotate idx; prefetch idx(t+2); issue gather(t+1) ----
        rcur = rnext; ccur = cnext;
        {
            int t2 = min(t + 2, t1 - 1);
            uint2 b = sed[t2 * 64 + ge];
            rnext = (int)b.x; cnext = (int)b.y;
        }
        if (t + 1 < t1) {
            const uint4* ap = (const uint4*)(pa + (size_t)rcur * 128 + 32 * gq);
            const uint4* bp = (const uint4*)(pb + (size_t)ccur * 128 + 32 * gq);
            ga0 = ap[0]; ga1 = ap[1]; ga2 = ap[2]; ga3 = ap[3];
            gb0 = bp[0]; gb1 = bp[1]; gb2 = bp[2]; gb3 = bp[3];
        }

        // ---- C: h/srow visible; single barrier per tile ----
        asm volatile("s_waitcnt lgkmcnt(0)\n\ts_barrier" ::: "memory");

        // ---- D: layer 2 MFMA, transposed: D[ch][edge] ----
        f32x4 acc2[2][2];
        #pragma unroll
        for (int m = 0; m < 2; ++m)
            #pragma unroll
            for (int n = 0; n < 2; ++n) {
                acc2[m][n][0] = b2v4[n].x; acc2[m][n][1] = b2v4[n].y;
                acc2[m][n][2] = b2v4[n].z; acc2[m][n][3] = b2v4[n].w;
            }
        __builtin_amdgcn_s_setprio(1);
        #pragma unroll
        for (int s = 0; s < 4; ++s) {
            half8 hb[2];
            #pragma unroll
            for (int m = 0; m < 2; ++m) {
                int e = w_e * 32 + 16 * m + l15;
                int sidx = e * 128 + ((32 * s + 8 * lg) ^ ((e & 15) << 3));
                hb[m] = *(const half8*)&h_lds[ib][sidx];
            }
            #pragma unroll
            for (int m = 0; m < 2; ++m)
                #pragma unroll
                for (int n = 0; n < 2; ++n)
                    acc2[m][n] = __builtin_amdgcn_mfma_f32_16x16x32_f16(
                        w2f[s][n], hb[m], acc2[m][n], 0, 0, 0);
        }
        __builtin_amdgcn_s_setprio(0);

        // ---- E: segmented max-scan across l15 (sorted rows) + tail atomics ----
        #pragma unroll
        for (int m = 0; m < 2; ++m) {
            int myrow = srow[ib][w_e * 32 + 16 * m + l15];
            f32x4 v0 = acc2[m][0], v1 = acc2[m][1];
            #pragma unroll
            for (int d = 1; d < 16; d <<= 1) {
                int pr = __shfl_up(myrow, d, 16);
                float a0 = __shfl_up(v0[0], d, 16), a1 = __shfl_up(v0[1], d, 16);
                float a2 = __shfl_up(v0[2], d, 16), a3 = __shfl_up(v0[3], d, 16);
                float c0 = __shfl_up(v1[0], d, 16), c1 = __shfl_up(v1[1], d, 16);
                float c2 = __shfl_up(v1[2], d, 16), c3 = __shfl_up(v1[3], d, 16);
                if (l15 >= d && pr == myrow) {
                    v0[0] = fmaxf(v0[0], a0); v0[1] = fmaxf(v0[1], a1);
                    v0[2] = fmaxf(v0[2], a2); v0[3] = fmaxf(v0[3], a3);
                    v1[0] = fmaxf(v1[0], c0); v1[1] = fmaxf(v1[1], c1);
                    v1[2] = fmaxf(v1[2], c2); v1[3] = fmaxf(v1[3], c3);
                }
            }
            int nr = __shfl_down(myrow, 1, 16);
            bool tail = (l15 == 15) || (nr != myrow);
            if (tail) {
                unsigned* dst = acc + (size_t)myrow * 128 + goff + w_h * 32 + 4 * lg;
                atomicMax(dst + 0,      enc(v0[0]));
                atomicMax(dst + 1,      enc(v0[1]));
                atomicMax(dst + 2,      enc(v0[2]));
                atomicMax(dst + 3,      enc(v0[3]));
                atomicMax(dst + 16 + 0, enc(v1[0]));
                atomicMax(dst + 16 + 1, enc(v1[1]));
                atomicMax(dst + 16 + 2, enc(v1[2]));
                atomicMax(dst + 16 + 3, enc(v1[3]));
            }
        }
    }
}

extern "C" void kernel_launch(void* const* d_in, const int* in_sizes, int n_in,
                              void* d_out, int out_size, void* d_ws, size_t ws_size,
                              hipStream_t stream) {
    const float* x1 = (const float*)d_in[0];
    const float* x2 = (const float*)d_in[1];
    const int*   ei1 = (const int*)d_in[2];
    const int*   ei2 = (const int*)d_in[3];
    const float* W1 = (const float*)d_in[4];
    const float* b1 = (const float*)d_in[5];
    const float* W2 = (const float*)d_in[6];
    const float* b2 = (const float*)d_in[7];
    unsigned* acc = (unsigned*)d_out;

    // workspace layout (u32 units)
    unsigned* w = (unsigned*)d_ws;
    unsigned* cnt     = w;                     // 100000
    unsigned* partial = w + 100000;            // 196
    unsigned* boff    = w + 100200;            // 196
    unsigned* cur     = w + 100400;            // 100000
    uint2*    se      = (uint2*)(w + 200400);  // 1.6M uint2 (12.8 MB)
    _Float16* pre     = (_Float16*)(w + 3400400); // 3*NN*128 f16 (38.4 MB)

    const int total = NN * 128;
    hipMemsetAsync(cnt, 0, 2 * NN * sizeof(unsigned), stream);
    hipMemsetAsync(acc, 0, (size_t)total * sizeof(unsigned), stream);

    hipLaunchKernelGGL(hist_k, dim3((2 * EE + 255) / 256), dim3(256), 0, stream,
                       ei1, ei2, cnt);
    hipLaunchKernelGGL(partial_k, dim3(2 * NB), dim3(512), 0, stream, cnt, partial);
    hipLaunchKernelGGL(boff_k, dim3(1), dim3(128), 0, stream, partial, boff);
    hipLaunchKernelGGL(cur_k, dim3(2 * NB), dim3(512), 0, stream, cnt, boff, cur);
    hipLaunchKernelGGL(scatter_k, dim3((2 * EE + 255) / 256), dim3(256), 0, stream,
                       ei1, ei2, cur, se);
    hipLaunchKernelGGL(pre_k, dim3(3 * NPB), dim3(256), 0, stream,
                       x1, x2, W1, b1, pre);
    hipLaunchKernelGGL(edge_mlp, dim3(2 * BPG), dim3(256), 0, stream,
                       pre, se, W2, b2, acc);
    hipLaunchKernelGGL(decode_acc, dim3((total + 255) / 256), dim3(256), 0, stream,
                       acc, total);
}

// Round 13
// 446.483 us; speedup vs baseline: 1.0337x; 1.0337x over previous
//
#include <hip/hip_runtime.h>

#define NN 50000
#define EE 800000
#define BPG 384                     // edge_mlp blocks per graph (row-partitioned)
#define RPB 131                     // rows per block (384*131 >= 50000)
#define NB 98                       // scan blocks per graph (98*512 >= 50000)
#define NPB 196                     // pre_k blocks per job

typedef _Float16 half8 __attribute__((ext_vector_type(8)));
typedef __attribute__((ext_vector_type(4))) float f32x4;
typedef __attribute__((ext_vector_type(4))) unsigned u32x4;

// order-preserving float->u32 encoding (0 = empty marker)
__device__ __forceinline__ unsigned enc(float f) {
    unsigned u = __float_as_uint(f);
    return u ^ (unsigned)(((int)u >> 31) | 0x80000000);
}
__device__ __forceinline__ float dec(unsigned u) {
    unsigned v = (u & 0x80000000u) ? (u & 0x7FFFFFFFu) : ~u;
    return __uint_as_float(v);
}

// ---------------- counting sort by destination row ----------------
__global__ void hist_k(const int* __restrict__ ei1, const int* __restrict__ ei2,
                       unsigned* __restrict__ cnt) {          // cnt[2][NN]
    int idx = blockIdx.x * blockDim.x + threadIdx.x;
    if (idx < EE)           atomicAdd(&cnt[ei1[idx]], 1u);
    else if (idx < 2 * EE)  atomicAdd(&cnt[NN + ei2[idx - EE]], 1u);
}

__global__ __launch_bounds__(512)
void partial_k(const unsigned* __restrict__ cnt, unsigned* __restrict__ partial) {
    int g = blockIdx.x / NB, b = blockIdx.x % NB;
    int i = b * 512 + threadIdx.x;
    unsigned x = (i < NN) ? cnt[g * NN + i] : 0u;
    #pragma unroll
    for (int o = 32; o; o >>= 1) x += __shfl_down(x, o, 64);
    __shared__ unsigned ws[8];
    int lane = threadIdx.x & 63, w = threadIdx.x >> 6;
    if (lane == 0) ws[w] = x;
    __syncthreads();
    if (threadIdx.x == 0) {
        unsigned s = 0;
        #pragma unroll
        for (int k = 0; k < 8; ++k) s += ws[k];
        partial[g * NB + b] = s;
    }
}

__global__ __launch_bounds__(128)
void boff_k(const unsigned* __restrict__ partial, unsigned* __restrict__ boff) {
    int g = threadIdx.x >> 6, lane = threadIdx.x & 63;
    const unsigned* p = partial + g * NB;
    unsigned* o = boff + g * NB;
    unsigned x0 = p[lane];
    unsigned v0 = x0;
    #pragma unroll
    for (int d = 1; d < 64; d <<= 1) { unsigned t = __shfl_up(v0, d, 64); if (lane >= d) v0 += t; }
    unsigned sum0 = __shfl(v0, 63, 64);
    unsigned x1 = (64 + lane < NB) ? p[64 + lane] : 0u;
    unsigned v1 = x1;
    #pragma unroll
    for (int d = 1; d < 64; d <<= 1) { unsigned t = __shfl_up(v1, d, 64); if (lane >= d) v1 += t; }
    o[lane] = v0 - x0;
    if (64 + lane < NB) o[64 + lane] = sum0 + v1 - x1;
}

__global__ __launch_bounds__(512)
void cur_k(const unsigned* __restrict__ cnt, const unsigned* __restrict__ boff,
           unsigned* __restrict__ cur, unsigned* __restrict__ off) {
    int g = blockIdx.x / NB, b = blockIdx.x % NB;
    int i = b * 512 + threadIdx.x;
    unsigned x = (i < NN) ? cnt[g * NN + i] : 0u;
    int lane = threadIdx.x & 63, w = threadIdx.x >> 6;
    unsigned v = x;
    #pragma unroll
    for (int d = 1; d < 64; d <<= 1) { unsigned t = __shfl_up(v, d, 64); if (lane >= d) v += t; }
    __shared__ unsigned ws[8], wso[8];
    if (lane == 63) ws[w] = v;
    __syncthreads();
    if (threadIdx.x < 8) {
        unsigned s = 0;
        for (int k = 0; k < (int)threadIdx.x; ++k) s += ws[k];
        wso[threadIdx.x] = s;
    }
    __syncthreads();
    if (i < NN) {
        unsigned e = boff[g * NB + b] + wso[w] + v - x;
        cur[g * NN + i] = e;
        off[g * (NN + 1) + i] = e;
    }
    if (b == 0 && threadIdx.x == 0) off[g * (NN + 1) + NN] = EE;
}

__global__ void scatter_k(const int* __restrict__ ei1, const int* __restrict__ ei2,
                          unsigned* __restrict__ cur, unsigned* __restrict__ se) {
    int idx = blockIdx.x * blockDim.x + threadIdx.x;
    if (idx < EE) {
        unsigned r = (unsigned)ei1[idx], c = (unsigned)ei1[EE + idx];
        unsigned p = atomicAdd(&cur[r], 1u);
        se[p] = (r << 16) | c;
    } else if (idx < 2 * EE) {
        int e = idx - EE;
        unsigned r = (unsigned)ei2[e], c = (unsigned)ei2[EE + e];
        unsigned p = atomicAdd(&cur[NN + r], 1u);
        se[EE + p] = (r << 16) | c;
    }
}

// ---------------- node-level precompute GEMMs (layer-1 algebra) ----------------
__global__ __launch_bounds__(256)
void pre_k(const float* __restrict__ x1, const float* __restrict__ x2,
           const float* __restrict__ W1, const float* __restrict__ b1,
           _Float16* __restrict__ pre)
{
    const int j  = blockIdx.x / NPB;
    const int bb = blockIdx.x % NPB;
    const float* __restrict__ xs = (j == 2) ? x2 : x1;
    _Float16* __restrict__ out = pre + (size_t)j * NN * 128;

    const int lane = threadIdx.x & 63;
    const int w    = threadIdx.x >> 6;
    const int l15  = lane & 15;
    const int lg   = lane >> 4;
    const int rowbase = bb * 256 + w * 64;

    half8 af[4][2];
    #pragma unroll
    for (int m = 0; m < 4; ++m)
        #pragma unroll
        for (int ks = 0; ks < 2; ++ks) {
            int row = rowbase + 16 * m + l15;
            if (row > NN - 1) row = NN - 1;
            const float* p = xs + (size_t)row * 64 + 32 * ks + 8 * lg;
            half8 r;
            #pragma unroll
            for (int i = 0; i < 8; ++i) r[i] = (_Float16)p[i];
            af[m][ks] = r;
        }

    #pragma unroll 2
    for (int n = 0; n < 8; ++n) {
        half8 bf[2];
        #pragma unroll
        for (int ks = 0; ks < 2; ++ks) {
            half8 r;
            #pragma unroll
            for (int i = 0; i < 8; ++i) {
                int k = 32 * ks + 8 * lg + i;
                int o = 16 * n + l15;
                float wv = (j == 0)
                    ? (W1[(size_t)k * 128 + o] - W1[(size_t)(64 + k) * 128 + o])
                    :  W1[(size_t)(64 + k) * 128 + o];
                r[i] = (_Float16)wv;
            }
            bf[ks] = r;
        }
        float binit = (j == 0) ? b1[16 * n + l15] : 0.0f;
        f32x4 acc[4];
        #pragma unroll
        for (int m = 0; m < 4; ++m) {
            acc[m][0] = binit; acc[m][1] = binit;
            acc[m][2] = binit; acc[m][3] = binit;
        }
        #pragma unroll
        for (int ks = 0; ks < 2; ++ks)
            #pragma unroll
            for (int m = 0; m < 4; ++m)
                acc[m] = __builtin_amdgcn_mfma_f32_16x16x32_f16(
                    af[m][ks], bf[ks], acc[m], 0, 0, 0);
        #pragma unroll
        for (int m = 0; m < 4; ++m)
            #pragma unroll
            for (int r = 0; r < 4; ++r) {
                int row = rowbase + 16 * m + 4 * lg + r;
                if (row < NN)
                    out[(size_t)row * 128 + 16 * n + l15] = (_Float16)acc[m][r];
            }
    }
}

// ---------------- main kernel: row-partitioned, zero global atomics ----------------
// Block owns rows [r0, r0+nr) and edges [off[r0], off[r0+nr]). Scan-merged
// tails -> LDS window atomicMax; epilogue decodes + plain coalesced stores.
__global__ __launch_bounds__(256, 2)
void edge_mlp(const _Float16* __restrict__ pre,
              const unsigned* __restrict__ se, const unsigned* __restrict__ off,
              const float* __restrict__ W2, const float* __restrict__ b2,
              float* __restrict__ out)
{
    __shared__ short h_lds[2][64 * 128];   // 32 KB, (e&15)<<3 XOR-swizzled
    __shared__ unsigned accw[RPB * 64];    // 33.5 KB enc-u32 window
    __shared__ int srow[2][64];

    const int tid  = threadIdx.x;
    const int lane = tid & 63;
    const int l15  = lane & 15;
    const int lg   = lane >> 4;
    const int wid  = tid >> 6;
    const int w_h  = wid & 1;
    const int w_e  = wid >> 1;

    const int g     = (blockIdx.x >= BPG) ? 1 : 0;
    const int bslot = g ? (blockIdx.x - BPG) : blockIdx.x;
    const unsigned* __restrict__ sed = se + (size_t)g * EE;
    const _Float16* __restrict__ pa = pre;
    const _Float16* __restrict__ pb = pre + (size_t)(1 + g) * NN * 128;
    const int goff = g * 64;

    const int r0 = bslot * RPB;
    if (r0 >= NN) return;
    const int nr = min(RPB, NN - r0);
    const int ebeg = (int)off[g * (NN + 1) + r0];
    const int eend = (int)off[g * (NN + 1) + r0 + nr];
    const int nt = (eend > ebeg) ? ((eend - ebeg + 63) >> 6) : 0;

    // init LDS accumulator window (0 = empty)
    for (int k = tid; k < nr * 64; k += 256) accw[k] = 0u;

    // W2^T A-frags
    half8 w2f[4][2];
    #pragma unroll
    for (int s = 0; s < 4; ++s)
        #pragma unroll
        for (int n = 0; n < 2; ++n) {
            const float* p = W2 + (size_t)(32 * s + 8 * lg) * 64
                               + (w_h * 32 + 16 * n + l15);
            half8 r;
            #pragma unroll
            for (int i = 0; i < 8; ++i) r[i] = (_Float16)p[i * 64];
            w2f[s][n] = r;
        }
    float4 b2v4[2];
    #pragma unroll
    for (int n = 0; n < 2; ++n)
        b2v4[n] = *(const float4*)(b2 + w_h * 32 + 16 * n + 4 * lg);

    const int ge = lane;
    const int gq = wid;
    const int swz = (ge & 15) << 3;
    const unsigned zu = 0u;

    if (nt > 0) {
        // ---- prologue ----
        int rcur, ccur, rnext, cnext;
        {
            int p0 = ebeg + ge; if (p0 >= eend) p0 = eend - 1;
            unsigned pk = sed[p0];
            rcur = (int)(pk >> 16); ccur = (int)(pk & 0xFFFFu);
            int p1 = ebeg + ((nt > 1) ? 64 : 0) + ge; if (p1 >= eend) p1 = eend - 1;
            pk = sed[p1];
            rnext = (int)(pk >> 16); cnext = (int)(pk & 0xFFFFu);
        }
        uint4 ga0, ga1, ga2, ga3, gb0, gb1, gb2, gb3;
        {
            const uint4* ap = (const uint4*)(pa + (size_t)rcur * 128 + 32 * gq);
            const uint4* bp = (const uint4*)(pb + (size_t)ccur * 128 + 32 * gq);
            ga0 = ap[0]; ga1 = ap[1]; ga2 = ap[2]; ga3 = ap[3];
            gb0 = bp[0]; gb1 = bp[1]; gb2 = bp[2]; gb3 = bp[3];
        }

        for (int t = 0; t < nt; ++t) {
            const int ib = t & 1;
            // ---- A: srow + h tile = relu(a + b) from prefetched regs ----
            if (tid < 64) srow[ib][tid] = rcur;
            {
                short* hrow = &h_lds[ib][ge * 128];
                u32x4 h;
                #define COMBINE(A, B, K)                                           \
                    {                                                              \
                        unsigned s0, s1, s2, s3;                                   \
                        asm("v_pk_add_f16 %0, %1, %2" : "=v"(s0) : "v"(A.x), "v"(B.x)); \
                        asm("v_pk_add_f16 %0, %1, %2" : "=v"(s1) : "v"(A.y), "v"(B.y)); \
                        asm("v_pk_add_f16 %0, %1, %2" : "=v"(s2) : "v"(A.z), "v"(B.z)); \
                        asm("v_pk_add_f16 %0, %1, %2" : "=v"(s3) : "v"(A.w), "v"(B.w)); \
                        asm("v_pk_max_f16 %0, %1, %2" : "=v"(s0) : "v"(s0), "v"(zu));   \
                        asm("v_pk_max_f16 %0, %1, %2" : "=v"(s1) : "v"(s1), "v"(zu));   \
                        asm("v_pk_max_f16 %0, %1, %2" : "=v"(s2) : "v"(s2), "v"(zu));   \
                        asm("v_pk_max_f16 %0, %1, %2" : "=v"(s3) : "v"(s3), "v"(zu));   \
                        h[0] = s0; h[1] = s1; h[2] = s2; h[3] = s3;                \
                        *(u32x4*)&hrow[(32 * gq + 8 * K) ^ swz] = h;               \
                    }
                COMBINE(ga0, gb0, 0)
                COMBINE(ga1, gb1, 1)
                COMBINE(ga2, gb2, 2)
                COMBINE(ga3, gb3, 3)
                #undef COMBINE
            }

            // ---- B: rotate idx; prefetch idx(t+2); issue gather(t+1) ----
            rcur = rnext; ccur = cnext;
            {
                int t2 = t + 2; if (t2 > nt - 1) t2 = nt - 1;
                int p2 = ebeg + t2 * 64 + ge; if (p2 >= eend) p2 = eend - 1;
                unsigned pk = sed[p2];
                rnext = (int)(pk >> 16); cnext = (int)(pk & 0xFFFFu);
            }
            if (t + 1 < nt) {
                const uint4* ap = (const uint4*)(pa + (size_t)rcur * 128 + 32 * gq);
                const uint4* bp = (const uint4*)(pb + (size_t)ccur * 128 + 32 * gq);
                ga0 = ap[0]; ga1 = ap[1]; ga2 = ap[2]; ga3 = ap[3];
                gb0 = bp[0]; gb1 = bp[1]; gb2 = bp[2]; gb3 = bp[3];
            }

            // ---- C: h/srow visible ----
            asm volatile("s_waitcnt lgkmcnt(0)\n\ts_barrier" ::: "memory");

            // ---- D: layer 2 MFMA, transposed: D[ch][edge] ----
            f32x4 acc2[2][2];
            #pragma unroll
            for (int m = 0; m < 2; ++m)
                #pragma unroll
                for (int n = 0; n < 2; ++n) {
                    acc2[m][n][0] = b2v4[n].x; acc2[m][n][1] = b2v4[n].y;
                    acc2[m][n][2] = b2v4[n].z; acc2[m][n][3] = b2v4[n].w;
                }
            __builtin_amdgcn_s_setprio(1);
            #pragma unroll
            for (int s = 0; s < 4; ++s) {
                half8 hb[2];
                #pragma unroll
                for (int m = 0; m < 2; ++m) {
                    int e = w_e * 32 + 16 * m + l15;
                    int sidx = e * 128 + ((32 * s + 8 * lg) ^ ((e & 15) << 3));
                    hb[m] = *(const half8*)&h_lds[ib][sidx];
                }
                #pragma unroll
                for (int m = 0; m < 2; ++m)
                    #pragma unroll
                    for (int n = 0; n < 2; ++n)
                        acc2[m][n] = __builtin_amdgcn_mfma_f32_16x16x32_f16(
                            w2f[s][n], hb[m], acc2[m][n], 0, 0, 0);
            }
            __builtin_amdgcn_s_setprio(0);

            // ---- E: segmented max-scan across l15 + LDS-window tail atomics ----
            #pragma unroll
            for (int m = 0; m < 2; ++m) {
                int myrow = srow[ib][w_e * 32 + 16 * m + l15];
                f32x4 v0 = acc2[m][0], v1 = acc2[m][1];
                #pragma unroll
                for (int d = 1; d < 16; d <<= 1) {
                    int pr = __shfl_up(myrow, d, 16);
                    float a0 = __shfl_up(v0[0], d, 16), a1 = __shfl_up(v0[1], d, 16);
                    float a2 = __shfl_up(v0[2], d, 16), a3 = __shfl_up(v0[3], d, 16);
                    float c0 = __shfl_up(v1[0], d, 16), c1 = __shfl_up(v1[1], d, 16);
                    float c2 = __shfl_up(v1[2], d, 16), c3 = __shfl_up(v1[3], d, 16);
                    if (l15 >= d && pr == myrow) {
                        v0[0] = fmaxf(v0[0], a0); v0[1] = fmaxf(v0[1], a1);
                        v0[2] = fmaxf(v0[2], a2); v0[3] = fmaxf(v0[3], a3);
                        v1[0] = fmaxf(v1[0], c0); v1[1] = fmaxf(v1[1], c1);
                        v1[2] = fmaxf(v1[2], c2); v1[3] = fmaxf(v1[3], c3);
                    }
                }
                int nrr = __shfl_down(myrow, 1, 16);
                bool tail = (l15 == 15) || (nrr != myrow);
                if (tail) {
                    unsigned* dst = &accw[(myrow - r0) * 64 + w_h * 32 + 4 * lg];
                    atomicMax(dst + 0,      enc(v0[0]));
                    atomicMax(dst + 1,      enc(v0[1]));
                    atomicMax(dst + 2,      enc(v0[2]));
                    atomicMax(dst + 3,      enc(v0[3]));
                    atomicMax(dst + 16 + 0, enc(v1[0]));
                    atomicMax(dst + 16 + 1, enc(v1[1]));
                    atomicMax(dst + 16 + 2, enc(v1[2]));
                    atomicMax(dst + 16 + 3, enc(v1[3]));
                }
            }
        }
    }

    // ---- epilogue: decode window, plain coalesced stores (unique writer) ----
    asm volatile("s_waitcnt lgkmcnt(0)\n\ts_barrier" ::: "memory");
    for (int idx = tid; idx < nr * 64; idx += 256) {
        int wr = idx >> 6, ch = idx & 63;
        unsigned u = accw[idx];
        out[(size_t)(r0 + wr) * 128 + goff + ch] = (u == 0u) ? 0.0f : dec(u);
    }
}

extern "C" void kernel_launch(void* const* d_in, const int* in_sizes, int n_in,
                              void* d_out, int out_size, void* d_ws, size_t ws_size,
                              hipStream_t stream) {
    const float* x1 = (const float*)d_in[0];
    const float* x2 = (const float*)d_in[1];
    const int*   ei1 = (const int*)d_in[2];
    const int*   ei2 = (const int*)d_in[3];
    const float* W1 = (const float*)d_in[4];
    const float* b1 = (const float*)d_in[5];
    const float* W2 = (const float*)d_in[6];
    const float* b2 = (const float*)d_in[7];
    float* out = (float*)d_out;

    // workspace layout (u32 units)
    unsigned* w = (unsigned*)d_ws;
    unsigned* cnt     = w;                     // 100000
    unsigned* partial = w + 100000;            // 196
    unsigned* boff    = w + 100200;            // 196
    unsigned* cur     = w + 100400;            // 100000
    unsigned* off     = w + 200400;            // 100002
    unsigned* se      = w + 300402;            // 1.6M u32 (6.4 MB)
    _Float16* pre     = (_Float16*)(w + 1900402); // 3*NN*128 f16 (38.4 MB)

    hipMemsetAsync(cnt, 0, 2 * NN * sizeof(unsigned), stream);
    hipLaunchKernelGGL(hist_k, dim3((2 * EE + 255) / 256), dim3(256), 0, stream,
                       ei1, ei2, cnt);
    hipLaunchKernelGGL(partial_k, dim3(2 * NB), dim3(512), 0, stream, cnt, partial);
    hipLaunchKernelGGL(boff_k, dim3(1), dim3(128), 0, stream, partial, boff);
    hipLaunchKernelGGL(cur_k, dim3(2 * NB), dim3(512), 0, stream, cnt, boff, cur, off);
    hipLaunchKernelGGL(scatter_k, dim3((2 * EE + 255) / 256), dim3(256), 0, stream,
                       ei1, ei2, cur, se);
    hipLaunchKernelGGL(pre_k, dim3(3 * NPB), dim3(256), 0, stream,
                       x1, x2, W1, b1, pre);
    hipLaunchKernelGGL(edge_mlp, dim3(2 * BPG), dim3(256), 0, stream,
                       pre, se, off, W2, b2, out);
}